// Round 7
// baseline (369.579 us; speedup 1.0000x reference)
//
#include <hip/hip_runtime.h>

typedef unsigned short u16;
typedef __attribute__((ext_vector_type(4))) short short4v;
typedef __attribute__((ext_vector_type(8))) short short8;
typedef __attribute__((ext_vector_type(4))) float f32x4;

#define MB_ (1024 * 1024)

__device__ __forceinline__ u16 f2bf(float f) {
  union { float f; unsigned int u; } v; v.f = f;
  unsigned int r = (v.u + 0x7FFFu + ((v.u >> 16) & 1u)) >> 16;  // RNE
  return (u16)r;
}

// pack two fp32 -> two bf16 (round-half-up) in one dword: low16 = a, high16 = b
__device__ __forceinline__ unsigned int pkbf(float a, float b) {
  union { float f; unsigned int u; } x, y; x.f = a; y.f = b;
  return __builtin_amdgcn_perm(y.u + 0x8000u, x.u + 0x8000u, 0x07060302u);
}

// single-instruction RNE pack (gfx950 v_cvt_pk_bf16_f32): low16 = a, high16 = b
__device__ __forceinline__ unsigned int cvtpk(float a, float b) {
  unsigned int r;
  asm("v_cvt_pk_bf16_f32 %0, %1, %2" : "=v"(r) : "v"(a), "v"(b));
  return r;
}

__device__ __forceinline__ void async16(const void* g, void* l) {
  __builtin_amdgcn_global_load_lds((__attribute__((address_space(1))) void*)g,
                                   (__attribute__((address_space(3))) void*)l, 16, 0, 0);
}

__device__ __forceinline__ f32x4 mfma32(short8 a, short8 b, f32x4 c) {
  return __builtin_amdgcn_mfma_f32_16x16x32_bf16(a, b, c, 0, 0, 0);
}

// 16x16x16 bf16 MFMA (A,B = 4 bf16 per lane). R5 verified the _1k builtin is the
// active path on this toolchain (conflict counter unchanged vs R1 -> no fallback).
#if __has_builtin(__builtin_amdgcn_mfma_f32_16x16x16bf16_1k)
#define MFMA16(a, b, c) __builtin_amdgcn_mfma_f32_16x16x16bf16_1k(a, b, c, 0, 0, 0)
#elif __has_builtin(__builtin_amdgcn_mfma_f32_16x16x16_bf16)
#define MFMA16(a, b, c) __builtin_amdgcn_mfma_f32_16x16x16_bf16(a, b, c, 0, 0, 0)
#else
__device__ __forceinline__ f32x4 mfma16_asm(short4v a, short4v b, f32x4 c) {
  asm("v_mfma_f32_16x16x16_bf16 %0, %1, %2, %0" : "+v"(c) : "v"(a), "v"(b));
  return c;
}
#define MFMA16(a, b, c) mfma16_asm(a, b, c)
#endif

// ---------------- kernel 1 (merged): activations fp32->bf16  +  weight transpose ----
// grid (8192, 4): y<3 -> cvt slab y; y==3 -> wtrans (x<4096, whole-block early out).
__global__ void prep(const float* __restrict__ qi, const float* __restrict__ ki,
                     const float* __restrict__ vi, u16* __restrict__ oq,
                     u16* __restrict__ okk, u16* __restrict__ ov,
                     const float* __restrict__ w0, const float* __restrict__ w1,
                     const float* __restrict__ w2, const float* __restrict__ w3,
                     u16* __restrict__ t0, u16* __restrict__ t1,
                     u16* __restrict__ t2, u16* __restrict__ t3) {
  if (blockIdx.y < 3) {
    const float* s = blockIdx.y == 0 ? qi : (blockIdx.y == 1 ? ki : vi);
    u16* d = blockIdx.y == 0 ? oq : (blockIdx.y == 1 ? okk : ov);
    size_t i = ((size_t)blockIdx.x * 256 + threadIdx.x) * 4;
    float4 f = *(const float4*)&s[i];
    ushort4 o;
    o.x = f2bf(f.x); o.y = f2bf(f.y); o.z = f2bf(f.z); o.w = f2bf(f.w);
    *(ushort4*)&d[i] = o;
    return;
  }
  // wtrans: W[k][n] -> Wt[n][k] bf16; 4096 blocks of 256 threads (reshaped 32x8)
  if (blockIdx.x >= 4096) return;
  const int z = blockIdx.x >> 10, xy = blockIdx.x & 1023;
  const float* in = z == 0 ? w0 : (z == 1 ? w1 : (z == 2 ? w2 : w3));
  u16* out = z == 0 ? t0 : (z == 1 ? t1 : (z == 2 ? t2 : t3));
  __shared__ float tile[32][33];
  const int bx = (xy & 31) * 32, by = (xy >> 5) * 32;
  const int tx = threadIdx.x & 31, ty = threadIdx.x >> 5;
  for (int i = ty; i < 32; i += 8)
    tile[i][tx] = in[(size_t)(by + i) * 1024 + bx + tx];
  __syncthreads();
  for (int i = ty; i < 32; i += 8)
    out[(size_t)(bx + i) * 1024 + by + tx] = f2bf(tile[tx][i]);
}

// ---------------- GEMM: C[8192,1024] = A[8192,1024] @ Bt[1024,1024]^T + bias ------
// m97 structure: 128x128 tile, BK=32, global_load_lds width 16, 4 waves, 4x4 MFMA/wave
// R4: 2-phase prefetch double-buffer. R5: T1 XCD swizzle (512 wg/slice, bijective)
// + setprio around the MFMA cluster — bundle measured ~ -22 µs, kept verbatim.
// mode 0: fp32 [m][n];  mode 1: bf16 split [B,H,S,DK];  mode 2: bf16 V^T [B,H,DK,S]
__device__ __forceinline__ void gemm_body(const u16* __restrict__ A, const u16* __restrict__ Bt,
                                          const float* __restrict__ bias, float alpha,
                                          int mode, void* __restrict__ outp) {
  __shared__ __align__(16) u16 As[2][128 * 32];
  __shared__ __align__(16) u16 Bs[2][128 * 32];
  const int t = threadIdx.x, wave = t >> 6, lane = t & 63;
  // XCD swizzle: flat id -> (xcd = flat%8) gets contiguous chunk of tile space
  const int flat = blockIdx.y * gridDim.x + blockIdx.x;
  const int per = (gridDim.x * gridDim.y) >> 3;        // 64 for 8x64 grid
  const int swz = (flat & 7) * per + (flat >> 3);
  const int m0 = (swz / gridDim.x) * 128, n0 = (swz % gridDim.x) * 128;
  const int wm = (wave >> 1) * 64, wn = (wave & 1) * 64;
  const int lrow = lane >> 2, lcol = (lane & 3) * 8;
  f32x4 acc[4][4] = {};

  auto stage = [&](int k0, int buf) {
#pragma unroll
    for (int c = 0; c < 2; ++c) {
      const int chunk = wave * 2 + c;
      const int row = chunk * 16 + lrow;
      async16(&A[(size_t)(m0 + row) * 1024 + k0 + lcol], &As[buf][chunk * 512]);
      async16(&Bt[(size_t)(n0 + row) * 1024 + k0 + lcol], &Bs[buf][chunk * 512]);
    }
  };

  stage(0, 0);
  __syncthreads();  // chunk 0 resident (syncthreads drains vmcnt(0))
  for (int k0 = 0; k0 < 1024; k0 += 32) {
    const int buf = (k0 >> 5) & 1;
    if (k0 < 992) stage(k0 + 32, buf ^ 1);  // prefetch next K-step into other buffer
    short8 af[4], bf[4];
#pragma unroll
    for (int mb = 0; mb < 4; ++mb)
      af[mb] = *(const short8*)&As[buf][(wm + mb * 16 + (lane & 15)) * 32 + (lane >> 4) * 8];
#pragma unroll
    for (int nb = 0; nb < 4; ++nb)
      bf[nb] = *(const short8*)&Bs[buf][(wn + nb * 16 + (lane & 15)) * 32 + (lane >> 4) * 8];
    __builtin_amdgcn_s_setprio(1);
#pragma unroll
    for (int mb = 0; mb < 4; ++mb)
#pragma unroll
      for (int nb = 0; nb < 4; ++nb)
        acc[mb][nb] = mfma32(af[mb], bf[nb], acc[mb][nb]);
    __builtin_amdgcn_s_setprio(0);
    __syncthreads();  // drains prefetch DMA + all waves done reading buf
  }
#pragma unroll
  for (int mb = 0; mb < 4; ++mb)
#pragma unroll
    for (int nb = 0; nb < 4; ++nb) {
      const int n = n0 + wn + nb * 16 + (lane & 15);
      const float bn = bias[n];
      if (mode == 2) {
        // V^T [B*H, DK, S]: r -> s contiguous, pack 4 into one 8B store
        const int h = n >> 6, d = n & 63;
        const int mbase = m0 + wm + mb * 16 + (lane >> 4) * 4;
        const int b = mbase >> 11, s = mbase & 2047;
        union { unsigned int u[2]; ushort4 s4; } pk;
        pk.u[0] = pkbf(acc[mb][nb][0] + bn, acc[mb][nb][1] + bn);
        pk.u[1] = pkbf(acc[mb][nb][2] + bn, acc[mb][nb][3] + bn);
        *(ushort4*)&((u16*)outp)[(size_t)((b * 16 + h) * 64 + d) * 2048 + s] = pk.s4;
      } else if (mode == 1) {
#pragma unroll
        for (int r = 0; r < 4; ++r) {
          const int m = m0 + wm + mb * 16 + (lane >> 4) * 4 + r;
          const int b = m >> 11, s = m & 2047, h = n >> 6, d = n & 63;
          ((u16*)outp)[(size_t)((b * 16 + h) * 2048 + s) * 64 + d] =
              f2bf(acc[mb][nb][r] * alpha + bn * alpha);
        }
      } else {
#pragma unroll
        for (int r = 0; r < 4; ++r) {
          const int m = m0 + wm + mb * 16 + (lane >> 4) * 4 + r;
          ((float*)outp)[(size_t)m * 1024 + n] = acc[mb][nb][r] + bn;
        }
      }
    }
}

__global__ __launch_bounds__(256, 3) void gemm_proj(
    const u16* xq, const u16* xk, const u16* xv,
    const u16* wq, const u16* wk, const u16* wv,
    const float* bq, const float* bk, const float* bv,
    u16* oq, u16* ok, u16* ov, float aq) {
  const int z = blockIdx.z;
  const u16* A = z == 0 ? xq : (z == 1 ? xk : xv);
  const u16* B = z == 0 ? wq : (z == 1 ? wk : wv);
  const float* bi = z == 0 ? bq : (z == 1 ? bk : bv);
  void* o = z == 0 ? (void*)oq : (z == 1 ? (void*)ok : (void*)ov);
  gemm_body(A, B, bi, z == 0 ? aq : 1.0f, z == 2 ? 2 : 1, o);
}

__global__ __launch_bounds__(256, 3) void gemm_out(const u16* A, const u16* Bt,
                                                   const float* bias, float* o) {
  gemm_body(A, Bt, bias, 1.0f, 0, o);
}

// ---------------- kernel 4: flash attention, S^T formulation, 64-q blocks --------
// R1-verified staging/sync, frozen. R7 deltas (compute-region only, VALU cuts):
//  (a) l accumulated on the MFMA pipe: lacc = MFMA16(ones, pk[kb], lacc) — the
//      all-ones A-frag makes every C row = sum_k P[k][q15]. Replaces 16 VALU
//      adds/chunk (~32 cy on the 72%-busy pipe) with 4 MFMA16 (~16 cy on the
//      37%-busy pipe), kills the serial p->l chain, and removes the epilogue
//      shfl reduction (lacc[0] is already the full sum, row-replicated).
//      l now sums the same bf16-rounded P used in PV (self-consistent).
//  (b) #pragma unroll 2 on the tk loop: hipcc won't unroll loops with barriers/
//      asm on its own; unrolling makes buf compile-time per copy so all 24
//      ds_read addresses fold to static base + 16-bit offset immediates.
// grid (S/64, B*H); block 256 = 4 waves; wave owns 16 q rows (one q-group).
// No online max (logits bounded; softmax shift-invariant).
// V arrives pre-transposed [B,H,DK,S]; K and V^T stage via async16 DMA.
// LDS XOR-chunk swizzle: 16B chunk c of row r at position c^(r&7).
__global__ __launch_bounds__(256, 5) void flash_attn(const u16* __restrict__ Q,
                                                     const u16* __restrict__ K,
                                                     const u16* __restrict__ Vt,
                                                     u16* __restrict__ O) {
  __shared__ __align__(16) u16 lds[2 * 2 * 64 * 64];  // [buf][Ks|Vs], 32 KB
  const int t = threadIdx.x, wave = t >> 6, lane = t & 63;
  const int quad = lane >> 4, q15 = lane & 15, sw = q15 & 7;
  const int bh = blockIdx.y, q0 = blockIdx.x * 64;
  const u16* Qb = Q + (size_t)bh * 2048 * 64;
  const u16* Kb = K + (size_t)bh * 2048 * 64;
  const u16* Vb = Vt + (size_t)bh * 64 * 2048;
  // Q B-fragments, held all loop: B[n=q][k=d]
  const int qr = q0 + wave * 16 + q15;
  const short8 qf0 = *(const short8*)&Qb[(size_t)qr * 64 + quad * 8];
  const short8 qf1 = *(const short8*)&Qb[(size_t)qr * 64 + 32 + quad * 8];
  f32x4 oacc[4] = {};  // O^T[d = mb*16 + quad*4 + r][q = lane&15]
  f32x4 lacc = {};     // every row = sum_k P[k][q = lane&15]
  const short4v ones4 = {(short)0x3F80, (short)0x3F80, (short)0x3F80, (short)0x3F80};

  // stage one 64-k chunk (K rows + V^T rows) into buffer `buf`; 4 loads/thread
  auto stage = [&](int kc, int buf) {
    u16* Ksb = lds + buf * 8192;
    u16* Vsb = Ksb + 4096;
#pragma unroll
    for (int c = 0; c < 2; ++c) {
      const int i = wave * 2 + c;
      const int row = i * 8 + (lane >> 3);          // s-row for K, d-row for V^T
      const int ch = (lane & 7) ^ (row & 7);        // swizzle via SOURCE permutation
      async16(&Kb[(size_t)(kc + row) * 64 + ch * 8], &Ksb[i * 512]);
      async16(&Vb[(size_t)row * 2048 + kc + ch * 8], &Vsb[i * 512]);
    }
  };

  stage(0, 0);
#pragma unroll 2
  for (int tk = 0; tk < 32; ++tk) {
    const int buf = tk & 1;
    if (tk < 31) {
      stage((tk + 1) * 64, buf ^ 1);                 // prefetch next chunk
      asm volatile("s_waitcnt vmcnt(4)" ::: "memory");  // cur's 4 loads done; next's stay in flight
    } else {
      asm volatile("s_waitcnt vmcnt(0)" ::: "memory");
    }
    __builtin_amdgcn_s_barrier();                    // all waves' cur-chunk DMA visible
    asm volatile("" ::: "memory");
    const u16* Ks = lds + buf * 8192;
    const u16* Vs = Ks + 4096;
    short4v pk[4];  // P^T C-frag == 16x16x16 B-frag — no LDS round-trip
#pragma unroll
    for (int ma = 0; ma < 4; ++ma) {
      const int rowo = (ma * 16 + q15) * 64;
      const short8 k0 = *(const short8*)&Ks[rowo + ((quad ^ sw) * 8)];
      const short8 k1 = *(const short8*)&Ks[rowo + (((4 + quad) ^ sw) * 8)];
      f32x4 s0 = {};
      s0 = mfma32(k0, qf0, s0);
      s0 = mfma32(k1, qf1, s0);
      float p0 = __builtin_exp2f(s0[0]);
      float p1 = __builtin_exp2f(s0[1]);
      float p2 = __builtin_exp2f(s0[2]);
      float p3 = __builtin_exp2f(s0[3]);
      union { unsigned int u[2]; short4v s4; } pq;
      pq.u[0] = cvtpk(p0, p1);
      pq.u[1] = cvtpk(p2, p3);
      pk[ma] = pq.s4;
    }
    // O^T += V^T · P^T ; l += ones · P^T (on the MFMA pipe)
#pragma unroll
    for (int mb = 0; mb < 4; ++mb) {
      const int vrow = (mb * 16 + q15) * 64;
#pragma unroll
      for (int kb = 0; kb < 4; ++kb) {
        const int pos = (((kb * 2 + (quad >> 1)) ^ sw) * 8) + (quad & 1) * 4;
        const short4v vf = *(const short4v*)&Vs[vrow + pos];
        oacc[mb] = MFMA16(vf, pk[kb], oacc[mb]);
      }
    }
#pragma unroll
    for (int kb = 0; kb < 4; ++kb) lacc = MFMA16(ones4, pk[kb], lacc);
    asm volatile("" ::: "memory");
    __builtin_amdgcn_s_barrier();  // all waves done reading buf before next DMA overwrites it
  }
  const float inv = 1.f / lacc[0];  // full k-sum for q15, replicated across rows
  // epilogue: un-transpose O^T via per-wave LDS tile (16x64), write [B,S,H*DK] bf16
  __syncthreads();               // other waves done reading Ks/Vs of last chunk
  u16* Es = lds + wave * 1024;   // 2 KB per wave
#pragma unroll
  for (int mb = 0; mb < 4; ++mb) {
    const int posc = ((mb * 2 + (quad >> 1)) ^ sw) * 8 + (quad & 1) * 4;
    union { unsigned int u[2]; ushort4 s4; } pq;
    pq.u[0] = cvtpk(oacc[mb][0] * inv, oacc[mb][1] * inv);
    pq.u[1] = cvtpk(oacc[mb][2] * inv, oacc[mb][3] * inv);
    *(ushort4*)&Es[q15 * 64 + posc] = pq.s4;
  }
  // wave-local write->read: compiler inserts lgkmcnt wait; no cross-wave dependency
  const int b = bh >> 4, h = bh & 15;
#pragma unroll
  for (int pass = 0; pass < 2; ++pass) {
    const int rw = pass * 8 + (lane >> 3);
    const int j = lane & 7;
    const short8 val = *(const short8*)&Es[rw * 64 + ((j ^ (rw & 7)) * 8)];
    *(short8*)&O[((size_t)(b * 2048 + q0 + wave * 16 + rw)) * 1024 + h * 64 + j * 8] = val;
  }
}

// ---------------- host launcher ----------------
extern "C" void kernel_launch(void* const* d_in, const int* in_sizes, int n_in,
                              void* d_out, int out_size, void* d_ws, size_t ws_size,
                              hipStream_t stream) {
  const float* q_in = (const float*)d_in[0];
  const float* v_in = (const float*)d_in[1];
  const float* k_in = (const float*)d_in[2];
  const float* Wq = (const float*)d_in[3];
  const float* bq = (const float*)d_in[4];
  const float* Wk = (const float*)d_in[5];
  const float* bk = (const float*)d_in[6];
  const float* Wv = (const float*)d_in[7];
  const float* bv = (const float*)d_in[8];
  const float* Wo = (const float*)d_in[9];
  const float* bo = (const float*)d_in[10];
  float* out = (float*)d_out;
  char* ws = (char*)d_ws;

  u16* xq = (u16*)(ws);                 // 16 MB  (bf16 activations)
  u16* xk = (u16*)(ws + 16 * (size_t)MB_);
  u16* xv = (u16*)(ws + 32 * (size_t)MB_);
  u16* wqT = (u16*)(ws + 48 * (size_t)MB_);  // 2 MB each (bf16 W^T)
  u16* wkT = (u16*)(ws + 50 * (size_t)MB_);
  u16* wvT = (u16*)(ws + 52 * (size_t)MB_);
  u16* woT = (u16*)(ws + 54 * (size_t)MB_);
  u16* qb = (u16*)(ws + 56 * (size_t)MB_);   // [B,H,S,DK] bf16
  u16* kb = (u16*)(ws + 72 * (size_t)MB_);   // [B,H,S,DK] bf16
  u16* vb = (u16*)(ws + 88 * (size_t)MB_);   // [B,H,DK,S] bf16 (pre-transposed)
  u16* ao = xq;  // attention output reuses xq (dead after projections)

  // fold softmax scale and log2(e) into Q so the inner loop uses raw exp2
  const float aq = 0.125f * 1.44269504088896340736f;

  prep<<<dim3(8192, 4), 256, 0, stream>>>(q_in, k_in, v_in, xq, xk, xv,
                                          Wq, Wk, Wv, Wo, wqT, wkT, wvT, woT);
  gemm_proj<<<dim3(8, 64, 3), 256, 0, stream>>>(xq, xk, xv, wqT, wkT, wvT, bq, bk, bv, qb, kb, vb, aq);
  flash_attn<<<dim3(32, 64), 256, 0, stream>>>(qb, kb, vb, ao);
  gemm_out<<<dim3(8, 64), 256, 0, stream>>>(ao, woT, bo, out);
}

// Round 9
// 360.916 us; speedup vs baseline: 1.0240x; 1.0240x over previous
//
#include <hip/hip_runtime.h>

typedef unsigned short u16;
typedef __attribute__((ext_vector_type(4))) short short4v;
typedef __attribute__((ext_vector_type(8))) short short8;
typedef __attribute__((ext_vector_type(4))) float f32x4;

#define MB_ (1024 * 1024)

__device__ __forceinline__ u16 f2bf(float f) {
  union { float f; unsigned int u; } v; v.f = f;
  unsigned int r = (v.u + 0x7FFFu + ((v.u >> 16) & 1u)) >> 16;  // RNE
  return (u16)r;
}

// pack two fp32 -> two bf16 (round-half-up) in one dword: low16 = a, high16 = b
__device__ __forceinline__ unsigned int pkbf(float a, float b) {
  union { float f; unsigned int u; } x, y; x.f = a; y.f = b;
  return __builtin_amdgcn_perm(y.u + 0x8000u, x.u + 0x8000u, 0x07060302u);
}

// single-instruction RNE pack (gfx950 v_cvt_pk_bf16_f32): low16 = a, high16 = b
__device__ __forceinline__ unsigned int cvtpk(float a, float b) {
  unsigned int r;
  asm("v_cvt_pk_bf16_f32 %0, %1, %2" : "=v"(r) : "v"(a), "v"(b));
  return r;
}

__device__ __forceinline__ void async16(const void* g, void* l) {
  __builtin_amdgcn_global_load_lds((__attribute__((address_space(1))) void*)g,
                                   (__attribute__((address_space(3))) void*)l, 16, 0, 0);
}

__device__ __forceinline__ f32x4 mfma32(short8 a, short8 b, f32x4 c) {
  return __builtin_amdgcn_mfma_f32_16x16x32_bf16(a, b, c, 0, 0, 0);
}

// 16x16x16 bf16 MFMA (A,B = 4 bf16 per lane). R5 verified the _1k builtin is the
// active path on this toolchain (conflict counter unchanged vs R1 -> no fallback).
#if __has_builtin(__builtin_amdgcn_mfma_f32_16x16x16bf16_1k)
#define MFMA16(a, b, c) __builtin_amdgcn_mfma_f32_16x16x16bf16_1k(a, b, c, 0, 0, 0)
#elif __has_builtin(__builtin_amdgcn_mfma_f32_16x16x16_bf16)
#define MFMA16(a, b, c) __builtin_amdgcn_mfma_f32_16x16x16_bf16(a, b, c, 0, 0, 0)
#else
__device__ __forceinline__ f32x4 mfma16_asm(short4v a, short4v b, f32x4 c) {
  asm("v_mfma_f32_16x16x16_bf16 %0, %1, %2, %0" : "+v"(c) : "v"(a), "v"(b));
  return c;
}
#define MFMA16(a, b, c) mfma16_asm(a, b, c)
#endif

// ---------------- kernel 1 (merged): activations fp32->bf16  +  weight transpose ----
// grid (8192, 4): y<3 -> cvt slab y; y==3 -> wtrans (x<4096, whole-block early out).
__global__ void prep(const float* __restrict__ qi, const float* __restrict__ ki,
                     const float* __restrict__ vi, u16* __restrict__ oq,
                     u16* __restrict__ okk, u16* __restrict__ ov,
                     const float* __restrict__ w0, const float* __restrict__ w1,
                     const float* __restrict__ w2, const float* __restrict__ w3,
                     u16* __restrict__ t0, u16* __restrict__ t1,
                     u16* __restrict__ t2, u16* __restrict__ t3) {
  if (blockIdx.y < 3) {
    const float* s = blockIdx.y == 0 ? qi : (blockIdx.y == 1 ? ki : vi);
    u16* d = blockIdx.y == 0 ? oq : (blockIdx.y == 1 ? okk : ov);
    size_t i = ((size_t)blockIdx.x * 256 + threadIdx.x) * 4;
    float4 f = *(const float4*)&s[i];
    ushort4 o;
    o.x = f2bf(f.x); o.y = f2bf(f.y); o.z = f2bf(f.z); o.w = f2bf(f.w);
    *(ushort4*)&d[i] = o;
    return;
  }
  // wtrans: W[k][n] -> Wt[n][k] bf16; 4096 blocks of 256 threads (reshaped 32x8)
  if (blockIdx.x >= 4096) return;
  const int z = blockIdx.x >> 10, xy = blockIdx.x & 1023;
  const float* in = z == 0 ? w0 : (z == 1 ? w1 : (z == 2 ? w2 : w3));
  u16* out = z == 0 ? t0 : (z == 1 ? t1 : (z == 2 ? t2 : t3));
  __shared__ float tile[32][33];
  const int bx = (xy & 31) * 32, by = (xy >> 5) * 32;
  const int tx = threadIdx.x & 31, ty = threadIdx.x >> 5;
  for (int i = ty; i < 32; i += 8)
    tile[i][tx] = in[(size_t)(by + i) * 1024 + bx + tx];
  __syncthreads();
  for (int i = ty; i < 32; i += 8)
    out[(size_t)(bx + i) * 1024 + by + tx] = f2bf(tile[tx][i]);
}

// ---------------- GEMM: C[8192,1024] = A[8192,1024] @ Bt[1024,1024]^T + bias ------
// m97 structure: 128x128 tile, BK=32, global_load_lds width 16, 4 waves, 4x4 MFMA/wave
// R4: 2-phase prefetch double-buffer. R5: T1 XCD swizzle + setprio (~ -22 µs bundle).
// mode 0: fp32 [m][n];  mode 1: bf16 split [B,H,S,DK];  mode 2: bf16 V^T [B,H,DK,S]
__device__ __forceinline__ void gemm_body(const u16* __restrict__ A, const u16* __restrict__ Bt,
                                          const float* __restrict__ bias, float alpha,
                                          int mode, void* __restrict__ outp) {
  __shared__ __align__(16) u16 As[2][128 * 32];
  __shared__ __align__(16) u16 Bs[2][128 * 32];
  const int t = threadIdx.x, wave = t >> 6, lane = t & 63;
  // XCD swizzle: flat id -> (xcd = flat%8) gets contiguous chunk of tile space
  const int flat = blockIdx.y * gridDim.x + blockIdx.x;
  const int per = (gridDim.x * gridDim.y) >> 3;        // 64 for 8x64 grid
  const int swz = (flat & 7) * per + (flat >> 3);
  const int m0 = (swz / gridDim.x) * 128, n0 = (swz % gridDim.x) * 128;
  const int wm = (wave >> 1) * 64, wn = (wave & 1) * 64;
  const int lrow = lane >> 2, lcol = (lane & 3) * 8;
  f32x4 acc[4][4] = {};

  auto stage = [&](int k0, int buf) {
#pragma unroll
    for (int c = 0; c < 2; ++c) {
      const int chunk = wave * 2 + c;
      const int row = chunk * 16 + lrow;
      async16(&A[(size_t)(m0 + row) * 1024 + k0 + lcol], &As[buf][chunk * 512]);
      async16(&Bt[(size_t)(n0 + row) * 1024 + k0 + lcol], &Bs[buf][chunk * 512]);
    }
  };

  stage(0, 0);
  __syncthreads();  // chunk 0 resident (syncthreads drains vmcnt(0))
  for (int k0 = 0; k0 < 1024; k0 += 32) {
    const int buf = (k0 >> 5) & 1;
    if (k0 < 992) stage(k0 + 32, buf ^ 1);  // prefetch next K-step into other buffer
    short8 af[4], bf[4];
#pragma unroll
    for (int mb = 0; mb < 4; ++mb)
      af[mb] = *(const short8*)&As[buf][(wm + mb * 16 + (lane & 15)) * 32 + (lane >> 4) * 8];
#pragma unroll
    for (int nb = 0; nb < 4; ++nb)
      bf[nb] = *(const short8*)&Bs[buf][(wn + nb * 16 + (lane & 15)) * 32 + (lane >> 4) * 8];
    __builtin_amdgcn_s_setprio(1);
#pragma unroll
    for (int mb = 0; mb < 4; ++mb)
#pragma unroll
      for (int nb = 0; nb < 4; ++nb)
        acc[mb][nb] = mfma32(af[mb], bf[nb], acc[mb][nb]);
    __builtin_amdgcn_s_setprio(0);
    __syncthreads();  // drains prefetch DMA + all waves done reading buf
  }
#pragma unroll
  for (int mb = 0; mb < 4; ++mb)
#pragma unroll
    for (int nb = 0; nb < 4; ++nb) {
      const int n = n0 + wn + nb * 16 + (lane & 15);
      const float bn = bias[n];
      if (mode == 2) {
        // V^T [B*H, DK, S]: r -> s contiguous, pack 4 into one 8B store
        const int h = n >> 6, d = n & 63;
        const int mbase = m0 + wm + mb * 16 + (lane >> 4) * 4;
        const int b = mbase >> 11, s = mbase & 2047;
        union { unsigned int u[2]; ushort4 s4; } pk;
        pk.u[0] = pkbf(acc[mb][nb][0] + bn, acc[mb][nb][1] + bn);
        pk.u[1] = pkbf(acc[mb][nb][2] + bn, acc[mb][nb][3] + bn);
        *(ushort4*)&((u16*)outp)[(size_t)((b * 16 + h) * 64 + d) * 2048 + s] = pk.s4;
      } else if (mode == 1) {
#pragma unroll
        for (int r = 0; r < 4; ++r) {
          const int m = m0 + wm + mb * 16 + (lane >> 4) * 4 + r;
          const int b = m >> 11, s = m & 2047, h = n >> 6, d = n & 63;
          ((u16*)outp)[(size_t)((b * 16 + h) * 2048 + s) * 64 + d] =
              f2bf(acc[mb][nb][r] * alpha + bn * alpha);
        }
      } else {
#pragma unroll
        for (int r = 0; r < 4; ++r) {
          const int m = m0 + wm + mb * 16 + (lane >> 4) * 4 + r;
          ((float*)outp)[(size_t)m * 1024 + n] = acc[mb][nb][r] + bn;
        }
      }
    }
}

__global__ __launch_bounds__(256, 3) void gemm_proj(
    const u16* xq, const u16* xk, const u16* xv,
    const u16* wq, const u16* wk, const u16* wv,
    const float* bq, const float* bk, const float* bv,
    u16* oq, u16* ok, u16* ov, float aq) {
  const int z = blockIdx.z;
  const u16* A = z == 0 ? xq : (z == 1 ? xk : xv);
  const u16* B = z == 0 ? wq : (z == 1 ? wk : wv);
  const float* bi = z == 0 ? bq : (z == 1 ? bk : bv);
  void* o = z == 0 ? (void*)oq : (z == 1 ? (void*)ok : (void*)ov);
  gemm_body(A, B, bi, z == 0 ? aq : 1.0f, z == 2 ? 2 : 1, o);
}

__global__ __launch_bounds__(256, 3) void gemm_out(const u16* A, const u16* Bt,
                                                   const float* bias, float* o) {
  gemm_body(A, Bt, bias, 1.0f, 0, o);
}

// ---------------- kernel 4: flash attention, S^T formulation, 64-q blocks --------
// R9: exact R6-verified body (122.6 µs; the R8 V-permutation REVERTED — 3rd
// index-refactor correctness failure, family condemned). One new, safe delta:
// T1 XCD-aware (bh,q0) swizzle. Old mapping round-robined the 32 same-bh blocks
// across all 8 XCDs -> every XCD L2 fetched ~every head's K/V (FETCH 139 MB vs
// ~64 unique). New: w = (flat%8)*256 + flat/8 (bijective, 2048=8*256) -> XCD k
// serves bh in [8k,8k+8), K+V = 8 x 512 KB = 4 MB = one XCD L2 exactly.
// grid (S/64, B*H); block 256 = 4 waves; wave owns 16 q rows (one q-group).
// No online max (logits bounded; softmax shift-invariant). l summed once at end.
// V arrives pre-transposed [B,H,DK,S]; K and V^T stage via async16 DMA.
// LDS XOR-chunk swizzle: 16B chunk c of row r at position c^(r&7).
__global__ __launch_bounds__(256, 5) void flash_attn(const u16* __restrict__ Q,
                                                     const u16* __restrict__ K,
                                                     const u16* __restrict__ Vt,
                                                     u16* __restrict__ O) {
  __shared__ __align__(16) u16 lds[2 * 2 * 64 * 64];  // [buf][Ks|Vs], 32 KB
  const int t = threadIdx.x, wave = t >> 6, lane = t & 63;
  const int quad = lane >> 4, q15 = lane & 15, sw = q15 & 7;
  // XCD swizzle: same-bh blocks grouped onto one XCD for K/V L2 residency
  const int flat = blockIdx.y * gridDim.x + blockIdx.x;
  const int w = (flat & 7) * 256 + (flat >> 3);
  const int bh = w >> 5, q0 = (w & 31) * 64;
  const u16* Qb = Q + (size_t)bh * 2048 * 64;
  const u16* Kb = K + (size_t)bh * 2048 * 64;
  const u16* Vb = Vt + (size_t)bh * 64 * 2048;
  // Q B-fragments, held all loop: B[n=q][k=d]
  const int qr = q0 + wave * 16 + q15;
  const short8 qf0 = *(const short8*)&Qb[(size_t)qr * 64 + quad * 8];
  const short8 qf1 = *(const short8*)&Qb[(size_t)qr * 64 + 32 + quad * 8];
  f32x4 oacc[4] = {};  // O^T[d = mb*16 + quad*4 + r][q = lane&15]
  float l = 0.f;

  // stage one 64-k chunk (K rows + V^T rows) into buffer `buf`; 4 loads/thread
  auto stage = [&](int kc, int buf) {
    u16* Ksb = lds + buf * 8192;
    u16* Vsb = Ksb + 4096;
#pragma unroll
    for (int c = 0; c < 2; ++c) {
      const int i = wave * 2 + c;
      const int row = i * 8 + (lane >> 3);          // s-row for K, d-row for V^T
      const int ch = (lane & 7) ^ (row & 7);        // swizzle via SOURCE permutation
      async16(&Kb[(size_t)(kc + row) * 64 + ch * 8], &Ksb[i * 512]);
      async16(&Vb[(size_t)row * 2048 + kc + ch * 8], &Vsb[i * 512]);
    }
  };

  stage(0, 0);
  for (int tk = 0; tk < 32; ++tk) {
    const int buf = tk & 1;
    if (tk < 31) {
      stage((tk + 1) * 64, buf ^ 1);                 // prefetch next chunk
      asm volatile("s_waitcnt vmcnt(4)" ::: "memory");  // cur's 4 loads done; next's stay in flight
    } else {
      asm volatile("s_waitcnt vmcnt(0)" ::: "memory");
    }
    __builtin_amdgcn_s_barrier();                    // all waves' cur-chunk DMA visible
    asm volatile("" ::: "memory");
    const u16* Ks = lds + buf * 8192;
    const u16* Vs = Ks + 4096;
    short4v pk[4];  // P^T C-frag == 16x16x16 B-frag — no LDS round-trip
#pragma unroll
    for (int ma = 0; ma < 4; ++ma) {
      const int rowo = (ma * 16 + q15) * 64;
      const short8 k0 = *(const short8*)&Ks[rowo + ((quad ^ sw) * 8)];
      const short8 k1 = *(const short8*)&Ks[rowo + (((4 + quad) ^ sw) * 8)];
      f32x4 s0 = {};
      s0 = mfma32(k0, qf0, s0);
      s0 = mfma32(k1, qf1, s0);
      float p0 = __builtin_exp2f(s0[0]);
      float p1 = __builtin_exp2f(s0[1]);
      float p2 = __builtin_exp2f(s0[2]);
      float p3 = __builtin_exp2f(s0[3]);
      l += (p0 + p1) + (p2 + p3);
      union { unsigned int u[2]; short4v s4; } pq;
      pq.u[0] = cvtpk(p0, p1);
      pq.u[1] = cvtpk(p2, p3);
      pk[ma] = pq.s4;
    }
    // O^T += V^T · P^T
#pragma unroll
    for (int mb = 0; mb < 4; ++mb) {
      const int vrow = (mb * 16 + q15) * 64;
#pragma unroll
      for (int kb = 0; kb < 4; ++kb) {
        const int pos = (((kb * 2 + (quad >> 1)) ^ sw) * 8) + (quad & 1) * 4;
        const short4v vf = *(const short4v*)&Vs[vrow + pos];
        oacc[mb] = MFMA16(vf, pk[kb], oacc[mb]);
      }
    }
    asm volatile("" ::: "memory");
    __builtin_amdgcn_s_barrier();  // all waves done reading buf before next DMA overwrites it
  }
  l += __shfl_xor(l, 16);
  l += __shfl_xor(l, 32);
  const float inv = 1.f / l;
  // epilogue: un-transpose O^T via per-wave LDS tile (16x64), write [B,S,H*DK] bf16
  __syncthreads();               // other waves done reading Ks/Vs of last chunk
  u16* Es = lds + wave * 1024;   // 2 KB per wave
#pragma unroll
  for (int mb = 0; mb < 4; ++mb) {
    const int posc = ((mb * 2 + (quad >> 1)) ^ sw) * 8 + (quad & 1) * 4;
    union { unsigned int u[2]; ushort4 s4; } pq;
    pq.u[0] = cvtpk(oacc[mb][0] * inv, oacc[mb][1] * inv);
    pq.u[1] = cvtpk(oacc[mb][2] * inv, oacc[mb][3] * inv);
    *(ushort4*)&Es[q15 * 64 + posc] = pq.s4;
  }
  // wave-local write->read: compiler inserts lgkmcnt wait; no cross-wave dependency
  const int b = bh >> 4, h = bh & 15;
#pragma unroll
  for (int pass = 0; pass < 2; ++pass) {
    const int rw = pass * 8 + (lane >> 3);
    const int j = lane & 7;
    const short8 val = *(const short8*)&Es[rw * 64 + ((j ^ (rw & 7)) * 8)];
    *(short8*)&O[((size_t)(b * 2048 + q0 + wave * 16 + rw)) * 1024 + h * 64 + j * 8] = val;
  }
}

// ---------------- host launcher ----------------
extern "C" void kernel_launch(void* const* d_in, const int* in_sizes, int n_in,
                              void* d_out, int out_size, void* d_ws, size_t ws_size,
                              hipStream_t stream) {
  const float* q_in = (const float*)d_in[0];
  const float* v_in = (const float*)d_in[1];
  const float* k_in = (const float*)d_in[2];
  const float* Wq = (const float*)d_in[3];
  const float* bq = (const float*)d_in[4];
  const float* Wk = (const float*)d_in[5];
  const float* bk = (const float*)d_in[6];
  const float* Wv = (const float*)d_in[7];
  const float* bv = (const float*)d_in[8];
  const float* Wo = (const float*)d_in[9];
  const float* bo = (const float*)d_in[10];
  float* out = (float*)d_out;
  char* ws = (char*)d_ws;

  u16* xq = (u16*)(ws);                 // 16 MB  (bf16 activations)
  u16* xk = (u16*)(ws + 16 * (size_t)MB_);
  u16* xv = (u16*)(ws + 32 * (size_t)MB_);
  u16* wqT = (u16*)(ws + 48 * (size_t)MB_);  // 2 MB each (bf16 W^T)
  u16* wkT = (u16*)(ws + 50 * (size_t)MB_);
  u16* wvT = (u16*)(ws + 52 * (size_t)MB_);
  u16* woT = (u16*)(ws + 54 * (size_t)MB_);
  u16* qb = (u16*)(ws + 56 * (size_t)MB_);   // [B,H,S,DK] bf16
  u16* kb = (u16*)(ws + 72 * (size_t)MB_);   // [B,H,S,DK] bf16
  u16* vb = (u16*)(ws + 88 * (size_t)MB_);   // [B,H,DK,S] bf16 (pre-transposed)
  u16* ao = xq;  // attention output reuses xq (dead after projections)

  // fold softmax scale and log2(e) into Q so the inner loop uses raw exp2
  const float aq = 0.125f * 1.44269504088896340736f;

  prep<<<dim3(8192, 4), 256, 0, stream>>>(q_in, k_in, v_in, xq, xk, xv,
                                          Wq, Wk, Wv, Wo, wqT, wkT, wvT, woT);
  gemm_proj<<<dim3(8, 64, 3), 256, 0, stream>>>(xq, xk, xv, wqT, wkT, wvT, bq, bk, bv, qb, kb, vb, aq);
  flash_attn<<<dim3(32, 64), 256, 0, stream>>>(qb, kb, vb, ao);
  gemm_out<<<dim3(8, 64), 256, 0, stream>>>(ao, woT, bo, out);
}